// Round 12
// baseline (189.402 us; speedup 1.0000x reference)
//
#include <hip/hip_runtime.h>
#include <hip/hip_bf16.h>
#include <math.h>

typedef __hip_bfloat16 bf16;
typedef __attribute__((ext_vector_type(8))) short frag8;
typedef __attribute__((ext_vector_type(4))) float f32x4;
typedef __attribute__((ext_vector_type(16))) float f32x16;
typedef __attribute__((ext_vector_type(2))) unsigned int u32x2;
typedef __attribute__((ext_vector_type(4))) unsigned int u32x4;

#define HW  1296
#define CH  128
#define TT  1327104   // 8 * 1296 * 128

#define SBAR() __builtin_amdgcn_sched_barrier(0)

__device__ __forceinline__ float b2f(bf16 v) { return __bfloat162float(v); }
__device__ __forceinline__ float bits2f(unsigned short u) {
    return __uint_as_float(((unsigned)u) << 16);
}
__device__ __forceinline__ float frcp(float x) { return __builtin_amdgcn_rcpf(x); }
__device__ __forceinline__ float fsigm(float x) { return frcp(1.0f + __expf(-x)); }
__device__ __forceinline__ float ftanh(float x) {
    float xc = fminf(15.0f, fmaxf(-15.0f, x));
    float e = __expf(2.0f * xc);
    return (e - 1.0f) * frcp(e + 1.0f);
}
// round-half-up f32->bf16 pair pack: 2 adds + 1 v_perm
__device__ __forceinline__ int packrh(float a, float b) {
    unsigned ua = __float_as_uint(a) + 0x8000u;
    unsigned ub = __float_as_uint(b) + 0x8000u;
    return (int)__builtin_amdgcn_perm(ub, ua, 0x07060302);
}
__device__ __forceinline__ int2 pack4(float a, float b, float c, float d) {
    int2 r; r.x = packrh(a, b); r.y = packrh(c, d); return r;
}
// packed RNE f32 pair -> bf16x2 in one VALU op
__device__ __forceinline__ unsigned cvtpk(float a, float b) {
    unsigned r;
    asm("v_cvt_pk_bf16_f32 %0, %1, %2" : "=v"(r) : "v"(a), "v"(b));
    return r;
}

// inline wave-uniform dtype detection (256 probe elems of w_in)
__device__ __forceinline__ int detect_f32(const void* w) {
    const short4* p = (const short4*)w;
    short4 v = p[threadIdx.x & 63];
    int bad = 0;
    #pragma unroll
    for (int j = 0; j < 4; ++j) {
        float f = bits2f(((const unsigned short*)&v)[j]);
        if (!(fabsf(f) <= 100.0f)) bad = 1;   // catches NaN/Inf too
    }
    return __any(bad) ? 1 : 0;
}

// ---------------- weight prep ----------------
// Wst (bf16): w_in[128o][128i]@0 | wconvT[9tap][128o][128r]@16384 |
//   wqkv[384o][128i]@163840 | wg[3][128o][256k]@212992 | wout[128o][128i]@311296
// Bst f32[768]: in@0 conv@128 i@256 g@384 o@512 out@640
// wq rows pre-scaled by log2(e) so attention uses exp2 directly.
__global__ __launch_bounds__(256) void k_prep(
    const void* w_in, const void* w_conv, const void* wq, const void* wk, const void* wv,
    const void* w_i, const void* w_g, const void* w_o, const void* w_out,
    const void* b_in, const void* b_conv, const void* b_i, const void* b_g,
    const void* b_o, const void* b_out,
    bf16* __restrict__ Wdst, float* __restrict__ Bdst)
{
    int idx = blockIdx.x * 256 + threadIdx.x;
    const int f = detect_f32(w_in);
    if (idx < 327680) {
        const void* src; int si;
        if (idx < 16384)       { src = w_in; si = idx; }   // native [o][i]
        else if (idx < 163840) { int j = idx - 16384; int tap = j >> 14, rem = j & 16383;
                                 int o = rem >> 7, r = rem & 127;
                                 src = w_conv; si = o * 2304 + r * 9 + tap; }
        else if (idx < 212992) { int j = idx - 163840; int o = j >> 7, i = j & 127;
                                 int ws_ = o >> 7;
                                 src = ws_ == 0 ? wq : ws_ == 1 ? wk : wv;
                                 si = (o & 127) * 128 + i; }
        else if (idx < 311296) { int j = idx - 212992; int g = j >> 15, rem = j & 32767;
                                 int o = rem >> 8, k = rem & 255;
                                 src = g == 0 ? w_i : g == 1 ? w_g : w_o; si = o * 256 + k; }
        else                   { int j = idx - 311296; int o = j >> 7, i = j & 127;
                                 src = w_out; si = o * 128 + i; }
        float v = f ? ((const float*)src)[si] : b2f(((const bf16*)src)[si]);
        if (idx >= 163840 && idx < 180224) v *= 1.4426950408889634f;  // wq * log2(e)
        Wdst[idx] = __float2bfloat16(v);
    } else if (idx < 327680 + 768) {
        int j = idx - 327680; int b = j >> 7, e = j & 127;
        const void* src = b == 0 ? b_in : b == 1 ? b_conv : b == 2 ? b_i
                        : b == 3 ? b_g : b == 4 ? b_o : b_out;
        Bdst[j] = f ? ((const float*)src)[e] : b2f(((const bf16*)src)[e]);
    }
}

// ---------------- k_inm: fused transpose + MFMA GEMM + tanh ----------------
// grid (8 n, 41 ptile, 4 otile) — n on blockIdx.x => per-batch XCD locality.
__global__ __launch_bounds__(256) void k_inm(const void* __restrict__ x,
                                             const void* __restrict__ wraw,
                                             const bf16* __restrict__ Wm,   // [o][i]
                                             const float* __restrict__ bias,
                                             bf16* __restrict__ XT) {
    __shared__ short Xl[32][132];
    const int tid = threadIdx.x, wave = tid >> 6, lane = tid & 63;
    const int quad = lane >> 4, l16 = lane & 15;
    const int n = blockIdx.x;
    const int pbase = blockIdx.y * 32;
    const int obase = blockIdx.z * 32 + (wave & 1) * 16;
    const int pstrip = (wave >> 1) * 16;
    const int f = detect_f32(wraw);

    // weight frags are LDS-independent: issue up front (overlap staging+barrier)
    frag8 WF[4];
    #pragma unroll
    for (int kc = 0; kc < 4; ++kc)
        WF[kc] = *(const frag8*)&Wm[(obase + l16) * CH + kc * 32 + quad * 8];

    #pragma unroll
    for (int rep = 0; rep < 4; ++rep) {
        int u = tid + rep * 256;
        int i = u >> 3;
        int p4 = (u & 7) * 4;
        int p = pbase + p4;
        short4 s = {0, 0, 0, 0};
        if (p < HW) {
            size_t gi = (size_t)n * CH * HW + (size_t)i * HW + p;
            if (f) {
                float4 fv = *(const float4*)((const float*)x + gi);
                int2 pk = pack4(fv.x, fv.y, fv.z, fv.w);
                s = *(short4*)&pk;
            } else {
                s = *(const short4*)((const bf16*)x + gi);
            }
        }
        Xl[p4 + 0][i] = s.x; Xl[p4 + 1][i] = s.y;
        Xl[p4 + 2][i] = s.z; Xl[p4 + 3][i] = s.w;
    }
    __syncthreads();

    const int pl = pstrip + l16;
    f32x4 acc = {0.f, 0.f, 0.f, 0.f};
    #pragma unroll
    for (int kc = 0; kc < 4; ++kc) {
        int k = kc * 32 + quad * 8;
        short4 b0 = *(const short4*)&Xl[pl][k];
        short4 b1 = *(const short4*)&Xl[pl][k + 4];
        frag8 bf = {b0.x, b0.y, b0.z, b0.w, b1.x, b1.y, b1.z, b1.w};
        acc = __builtin_amdgcn_mfma_f32_16x16x32_bf16(WF[kc], bf, acc, 0, 0, 0);
    }

    int p = pbase + pstrip + l16;
    if (p < HW) {
        int og = obase + quad * 4;
        int2 pk = pack4(ftanh(acc[0] + bias[og + 0]), ftanh(acc[1] + bias[og + 1]),
                        ftanh(acc[2] + bias[og + 2]), ftanh(acc[3] + bias[og + 3]));
        *(int2*)((short*)XT + ((size_t)n * HW + p) * CH + og) = pk;
    }
}

// ---------------- k_cq: FUSED 3x3 conv (tap-split x2, FENCED pipeline) + QKV ----------------
// grid (8 n, 41 ptile), 512 threads = 8 waves: (o4 = w&3 -> 32o, tg = w>>2 ->
// taps 0..4 / 5..8). r11 showed the scheduler reserializes batched loads into
// load->wait->MFMA chains regardless of VGPR budget (VGPR=56, ~200 serial L2
// latencies = 22us/block). sched_barrier(0) fences PIN the order:
// [loads tap t+1] | [MFMAs tap t] — 16 loads issue back-to-back, the waitcnt
// before tap t's MFMAs leaves tap t+1's loads in flight (one latency exposure
// per tap, AITER-style vmcnt(N)>0 pattern). Double-buffered frags ~128 VGPR;
// launch_bounds(512,1) allows it (grid 328 blocks ~1.3/CU, occupancy loss free).
__global__ __launch_bounds__(512, 1) void k_cq(
    const bf16* __restrict__ XT, const bf16* __restrict__ Wc,
    const float* __restrict__ bc, const bf16* __restrict__ Wqkv,
    bf16* __restrict__ Zb, bf16* __restrict__ Qb, bf16* __restrict__ Kb,
    bf16* __restrict__ Vb)
{
    __shared__ short Zl[32][136];        // 8.7 KB
    __shared__ float Rd[4][4][4][64];    // 16 KB: [o4][of*2+pt][reg][lane]
    const int tid = threadIdx.x, w = tid >> 6, lane = tid & 63;
    const int quad = lane >> 4, l16 = lane & 15;
    const int n = blockIdx.x;
    const int pbase = blockIdx.y * 32;
    const bf16* actn = XT + (size_t)n * HW * CH;

    // ---- conv phase: wave (o4, tg); 32o x 32p x {taps 0-4 | 5-8} ----
    const int o4 = w & 3, tg = w >> 2;
    const int obase = o4 * 32;
    const int p1 = pbase + l16, p2 = pbase + 16 + l16;
    const bool p1ok = p1 < HW, p2ok = p2 < HW;
    const int h1 = p1 / 36, w1 = p1 - h1 * 36;
    const int h2 = p2 / 36, w2 = p2 - h2 * 36;

    frag8 zf = {0, 0, 0, 0, 0, 0, 0, 0};
    f32x4 acc[2][2];   // [of][pt]
    #pragma unroll
    for (int of = 0; of < 2; ++of) {
        acc[of][0] = (f32x4){0.f, 0.f, 0.f, 0.f};
        acc[of][1] = (f32x4){0.f, 0.f, 0.f, 0.f};
    }

    frag8 A1[2][4], A2[2][4], W0[2][4], W1[2][4];   // double-buffered tap frags

    #define LOADTAP(TAP, BUF)                                                        \
    {                                                                                \
        constexpr int dy = (TAP) / 3 - 1, dx = (TAP) % 3 - 1;                        \
        const bool ok1 = p1ok && (unsigned)(h1 + dy) < 36u && (unsigned)(w1 + dx) < 36u; \
        const bool ok2 = p2ok && (unsigned)(h2 + dy) < 36u && (unsigned)(w2 + dx) < 36u; \
        const int sh = dy * 36 + dx;                                                 \
        const bf16* a1 = actn + (size_t)(p1 + sh) * CH + quad * 8;                   \
        const bf16* a2 = actn + (size_t)(p2 + sh) * CH + quad * 8;                   \
        const bf16* wp0 = Wc + (TAP) * 16384 + (obase + l16) * CH + quad * 8;        \
        const bf16* wp1 = Wc + (TAP) * 16384 + (obase + 16 + l16) * CH + quad * 8;   \
        _Pragma("unroll")                                                            \
        for (int kc = 0; kc < 4; ++kc) {                                             \
            A1[BUF][kc] = ok1 ? *(const frag8*)&a1[kc * 32] : zf;                    \
            A2[BUF][kc] = ok2 ? *(const frag8*)&a2[kc * 32] : zf;                    \
            W0[BUF][kc] = *(const frag8*)&wp0[kc * 32];                              \
            W1[BUF][kc] = *(const frag8*)&wp1[kc * 32];                              \
        }                                                                            \
    }

    #define MFMATAP(BUF)                                                             \
    {                                                                                \
        _Pragma("unroll")                                                            \
        for (int kc = 0; kc < 4; ++kc) {                                             \
            acc[0][0] = __builtin_amdgcn_mfma_f32_16x16x32_bf16(W0[BUF][kc], A1[BUF][kc], acc[0][0], 0, 0, 0); \
            acc[0][1] = __builtin_amdgcn_mfma_f32_16x16x32_bf16(W0[BUF][kc], A2[BUF][kc], acc[0][1], 0, 0, 0); \
            acc[1][0] = __builtin_amdgcn_mfma_f32_16x16x32_bf16(W1[BUF][kc], A1[BUF][kc], acc[1][0], 0, 0, 0); \
            acc[1][1] = __builtin_amdgcn_mfma_f32_16x16x32_bf16(W1[BUF][kc], A2[BUF][kc], acc[1][1], 0, 0, 0); \
        }                                                                            \
    }

    if (tg == 0) {
        LOADTAP(0, 0) SBAR();
        LOADTAP(1, 1) SBAR();
        MFMATAP(0)    SBAR();
        LOADTAP(2, 0) SBAR();
        MFMATAP(1)    SBAR();
        LOADTAP(3, 1) SBAR();
        MFMATAP(0)    SBAR();
        LOADTAP(4, 0) SBAR();
        MFMATAP(1)    SBAR();
        MFMATAP(0)
    } else {
        LOADTAP(5, 0) SBAR();
        LOADTAP(6, 1) SBAR();
        MFMATAP(0)    SBAR();
        LOADTAP(7, 0) SBAR();
        MFMATAP(1)    SBAR();
        LOADTAP(8, 1) SBAR();
        MFMATAP(0)    SBAR();
        MFMATAP(1)
    }
    #undef LOADTAP
    #undef MFMATAP

    // tg=1 publishes partials; tg=0 reduces + epilogue
    if (tg == 1) {
        #pragma unroll
        for (int of = 0; of < 2; ++of)
            #pragma unroll
            for (int pt = 0; pt < 2; ++pt)
                #pragma unroll
                for (int r = 0; r < 4; ++r)
                    Rd[o4][of * 2 + pt][r][lane] = acc[of][pt][r];
    }
    __syncthreads();
    if (tg == 0) {
        #pragma unroll
        for (int of = 0; of < 2; ++of) {
            #pragma unroll
            for (int pt = 0; pt < 2; ++pt) {
                #pragma unroll
                for (int r = 0; r < 4; ++r)
                    acc[of][pt][r] += Rd[o4][of * 2 + pt][r][lane];
                int og = obase + of * 16 + quad * 4;
                int pl = pt * 16 + l16;
                int p = pbase + pl;
                int2 pk = pack4(acc[of][pt][0] + bc[og + 0], acc[of][pt][1] + bc[og + 1],
                                acc[of][pt][2] + bc[og + 2], acc[of][pt][3] + bc[og + 3]);
                *(int2*)&Zl[pl][og] = pk;
                if (p < HW)
                    *(int2*)((short*)Zb + ((size_t)n * HW + p) * CH + og) = pk;
            }
        }
    }
    __syncthreads();

    // ---- qkv phase (verified r8/r9 scheme; fence between loads and MFMAs) ----
    for (int ot = w; ot < 12; ot += 8) {
        const bool vt = (ot >= 8);          // wave-uniform
        const int ob = ot * 32;
        frag8 B1[4], B2[4], W0a[4], W1a[4];
        #pragma unroll
        for (int kc = 0; kc < 4; ++kc) {
            int ko = kc * 32 + quad * 8;
            B1[kc]  = *(const frag8*)&Zl[l16][ko];
            B2[kc]  = *(const frag8*)&Zl[16 + l16][ko];
            W0a[kc] = *(const frag8*)&Wqkv[(size_t)(ob + l16) * CH + ko];
            W1a[kc] = *(const frag8*)&Wqkv[(size_t)(ob + 16 + l16) * CH + ko];
        }
        SBAR();

        f32x4 qacc[2][2];   // [of][pt]
        #pragma unroll
        for (int of = 0; of < 2; ++of) {
            qacc[of][0] = (f32x4){0.f, 0.f, 0.f, 0.f};
            qacc[of][1] = (f32x4){0.f, 0.f, 0.f, 0.f};
        }
        #pragma unroll
        for (int kc = 0; kc < 4; ++kc) {
            if (vt) {
                qacc[0][0] = __builtin_amdgcn_mfma_f32_16x16x32_bf16(B1[kc], W0a[kc], qacc[0][0], 0, 0, 0);
                qacc[0][1] = __builtin_amdgcn_mfma_f32_16x16x32_bf16(B2[kc], W0a[kc], qacc[0][1], 0, 0, 0);
                qacc[1][0] = __builtin_amdgcn_mfma_f32_16x16x32_bf16(B1[kc], W1a[kc], qacc[1][0], 0, 0, 0);
                qacc[1][1] = __builtin_amdgcn_mfma_f32_16x16x32_bf16(B2[kc], W1a[kc], qacc[1][1], 0, 0, 0);
            } else {
                qacc[0][0] = __builtin_amdgcn_mfma_f32_16x16x32_bf16(W0a[kc], B1[kc], qacc[0][0], 0, 0, 0);
                qacc[0][1] = __builtin_amdgcn_mfma_f32_16x16x32_bf16(W0a[kc], B2[kc], qacc[0][1], 0, 0, 0);
                qacc[1][0] = __builtin_amdgcn_mfma_f32_16x16x32_bf16(W1a[kc], B1[kc], qacc[1][0], 0, 0, 0);
                qacc[1][1] = __builtin_amdgcn_mfma_f32_16x16x32_bf16(W1a[kc], B2[kc], qacc[1][1], 0, 0, 0);
            }
        }

        if (vt) {
            #pragma unroll
            for (int of = 0; of < 2; ++of) {
                int ov = ob + of * 16 - 256 + l16;
                #pragma unroll
                for (int pt = 0; pt < 2; ++pt) {
                    int p4 = pbase + pt * 16 + quad * 4;
                    if (p4 >= HW) continue;
                    int2 pk = pack4(qacc[of][pt][0], qacc[of][pt][1], qacc[of][pt][2], qacc[of][pt][3]);
                    *(int2*)((short*)Vb + ((size_t)n * CH + ov) * HW + p4) = pk;
                }
            }
        } else {
            #pragma unroll
            for (int of = 0; of < 2; ++of) {
                int ogq = ob + of * 16 + quad * 4;
                int which = ogq >> 7, ol = ogq & 127;
                bf16* dst = which == 0 ? Qb : Kb;
                #pragma unroll
                for (int pt = 0; pt < 2; ++pt) {
                    int p = pbase + pt * 16 + l16;
                    if (p >= HW) continue;
                    size_t di = (((size_t)n * 8 + (ol >> 4)) * HW + p) * 16 + (ol & 15);
                    int2 pk = pack4(qacc[of][pt][0], qacc[of][pt][1], qacc[of][pt][2], qacc[of][pt][3]);
                    *(int2*)((short*)dst + di) = pk;
                }
            }
        }
    }
}

// ---------------- k_cell: gates GEMM + LSTM cell + fused out-projection ----------------
// grid (8 n, 81 ptile) — 81*16 = 1296 exactly, no p guards. Same fence
// treatment: LOADG blocks pinned before MFMA blocks (scheduler was
// reserializing the 2-deep pipeline — r3 showed VGPR=16).
__global__ __launch_bounds__(256, 1) void k_cell(
    const bf16* __restrict__ Zb, const bf16* __restrict__ Ab,
    const bf16* __restrict__ Wg, const float* __restrict__ bg,
    const bf16* __restrict__ Wo, const float* __restrict__ bo,
    void* __restrict__ out, const void* __restrict__ wraw)
{
    __shared__ short Hl[16][136];   // row stride 272B
    const int tid = threadIdx.x, w = tid >> 6, lane = tid & 63;
    const int quad = lane >> 4, l16 = lane & 15;
    const int n = blockIdx.x;
    const int pbase = blockIdx.y * 16;
    const int f32f = detect_f32(wraw);
    const bf16* zn = Zb + (size_t)n * HW * CH;
    const bf16* an = Ab + (size_t)n * HW * CH;

    const int obase = w * 32;
    const int p1 = pbase + l16;   // always < HW (81*16 == 1296)

    f32x4 acc[3][2];
    #pragma unroll
    for (int g = 0; g < 3; ++g) {
        acc[g][0] = (f32x4){0.f, 0.f, 0.f, 0.f};
        acc[g][1] = (f32x4){0.f, 0.f, 0.f, 0.f};
    }

    frag8 GB[2];
    frag8 GW[2][6];

    #define LOADG(KC, BUF)                                                           \
    {                                                                                \
        const bf16* src = ((KC) >= 4) ? an : zn;                                     \
        const int ko = ((KC) & 3) * 32 + quad * 8;                                   \
        GB[BUF] = *(const frag8*)&src[(size_t)p1 * CH + ko];                         \
        _Pragma("unroll")                                                            \
        for (int g = 0; g < 3; ++g) {                                                \
            _Pragma("unroll")                                                        \
            for (int of = 0; of < 2; ++of)                                           \
                GW[BUF][g * 2 + of] = *(const frag8*)&Wg[g * 32768 +                 \
                    (obase + of * 16 + l16) * 256 + (KC) * 32 + quad * 8];           \
        }                                                                            \
    }

    LOADG(0, 0);
    SBAR();
    #pragma unroll
    for (int kc = 0; kc < 8; ++kc) {
        const int cur = kc & 1;
        if (kc < 7) LOADG(kc + 1, cur ^ 1);
        SBAR();
        #pragma unroll
        for (int g = 0; g < 3; ++g) {
            #pragma unroll
            for (int of = 0; of < 2; ++of)
                acc[g][of] = __builtin_amdgcn_mfma_f32_16x16x32_bf16(
                    GW[cur][g * 2 + of], GB[cur], acc[g][of], 0, 0, 0);
        }
        SBAR();
    }
    #undef LOADG

    // cell nonlinearity -> LDS h tile (C layout: row o = quad*4+r, col p = l16)
    #pragma unroll
    for (int of = 0; of < 2; ++of) {
        int og = obase + of * 16 + quad * 4;
        float hv[4];
        #pragma unroll
        for (int r = 0; r < 4; ++r) {
            int o = og + r;
            float iv = fsigm(acc[0][of][r] + bg[o]);
            float gv = ftanh(acc[1][of][r] + bg[128 + o]);
            float ov = fsigm(acc[2][of][r] + bg[256 + o]);
            hv[r] = ov * ftanh(iv * gv);
        }
        *(int2*)&Hl[l16][og] = pack4(hv[0], hv[1], hv[2], hv[3]);
    }

    // out-phase weight frags: LDS-independent, issue before the barrier
    frag8 OW[2][4];
    #pragma unroll
    for (int of = 0; of < 2; ++of)
        #pragma unroll
        for (int kc = 0; kc < 4; ++kc)
            OW[of][kc] = *(const frag8*)&Wo[(size_t)(obase + of * 16 + l16) * CH
                                            + kc * 32 + quad * 8];
    __syncthreads();

    f32x4 oc[2];
    oc[0] = (f32x4){0.f, 0.f, 0.f, 0.f};
    oc[1] = (f32x4){0.f, 0.f, 0.f, 0.f};
    #pragma unroll
    for (int kc = 0; kc < 4; ++kc) {
        int k = kc * 32 + quad * 8;
        short4 h0 = *(const short4*)&Hl[l16][k];
        short4 h1 = *(const short4*)&Hl[l16][k + 4];
        frag8 af = {h0.x, h0.y, h0.z, h0.w, h1.x, h1.y, h1.z, h1.w};
        #pragma unroll
        for (int of = 0; of < 2; ++of)
            oc[of] = __builtin_amdgcn_mfma_f32_16x16x32_bf16(af, OW[of][kc], oc[of], 0, 0, 0);
    }
    int p4 = pbase + quad * 4;
    #pragma unroll
    for (int of = 0; of < 2; ++of) {
        int o = obase + of * 16 + l16;
        float bv = bo[o];
        size_t di = ((size_t)n * CH + o) * HW + p4;
        if (f32f) {
            float4 fv = {oc[of][0] + bv, oc[of][1] + bv, oc[of][2] + bv, oc[of][3] + bv};
            *(float4*)&((float*)out)[di] = fv;
        } else {
            int2 pk = pack4(oc[of][0] + bv, oc[of][1] + bv, oc[of][2] + bv, oc[of][3] + bv);
            *(int2*)&((short*)out)[di] = pk;
        }
    }
}

// ---------------- MFMA flash attention v7: 32x32x16, d-split x2, S-pipelined ----------------
// grid (8 n, 11 qtile, 8 head), 512 threads = 8 waves: qw = w&3 (32 q each),
// dq = w>>2 (d-halves: chunks 0..19 / 20..40). Partial O/L over disjoint
// d-ranges combine additively (LDS, one barrier).
// S layout (m74/m101): col=q=lane&31, row=d_local=(r&3)+8*(r>>2)+4*(lane>>5).
// lsum free: V A-operand row c==16 all-ones -> Oacc[8] = sum_d P[d][q].
__global__ __launch_bounds__(512) void k_attn(const bf16* __restrict__ Qg,
                                              const bf16* __restrict__ Kg,
                                              const bf16* __restrict__ Vcf,
                                              bf16* __restrict__ A) {
    __shared__ float Lc[4][9][64];   // [qw][acc reg 0..7 + lsum][lane]

    const int tid = threadIdx.x;
    const int w = tid >> 6, lane = tid & 63;
    const int l32 = lane & 31, hi = lane >> 5;
    const int qw = w & 3, dq = w >> 2;
    const int n = blockIdx.x;
    const int head = blockIdx.z;
    const int qb = blockIdx.y * 128 + qw * 32;
    const int qtok = qb + l32;

    const short* Qh = (const short*)Qg + ((size_t)(n * 8 + head)) * HW * 16;
    const short* Kh = (const short*)Kg + ((size_t)(n * 8 + head)) * HW * 16;
    const short* Vh = (const short*)Vcf + ((size_t)n * CH + head * 16) * HW;

    frag8 qf = {0, 0, 0, 0, 0, 0, 0, 0};
    if (qtok < HW) qf = *(const frag8*)&Qh[(size_t)qtok * 16 + hi * 8];

    const short one = (short)0x3F80;
    const frag8 vones = {one, one, one, one, one, one, one, one};
    const frag8 vzero = {0, 0, 0, 0, 0, 0, 0, 0};
    const frag8 vfill = (l32 == 16) ? vones : vzero;
    const bool vload = l32 < 16;
    const short* Vrow = Vh + (size_t)(vload ? l32 : 0) * HW;

    const f32x16 zero16 = {};
    f32x16 Oacc = {};

    auto KLD = [&](int dd) -> frag8 {
        return *(const frag8*)&Kh[(size_t)(dd + l32) * 16 + hi * 8];
    };
    auto VLD = [&](int dd) -> frag8 {
        return vload ? *(const frag8*)&Vrow[dd + hi * 8] : vfill;
    };

    const int c0 = dq ? 20 : 0;
    frag8 kf  = KLD(c0 * 32);
    frag8 kf2 = KLD(c0 * 32 + 32);
    frag8 va  = VLD(c0 * 32);
    frag8 vb  = VLD(c0 * 32 + 16);
    f32x16 S = __builtin_amdgcn_mfma_f32_32x32x16_bf16(kf, qf, zero16, 0, 0, 0);

    for (int it = 0; it < 20; ++it) {
        const int d0 = (c0 + it) * 32;
        frag8 kn  = KLD(d0 + 64);
        frag8 van = VLD(d0 + 32);
        frag8 vbn = VLD(d0 + 48);
        f32x16 Sn = __builtin_amdgcn_mfma_f32_32x32x16_bf16(kf2, qf, zero16, 0, 0, 0);

        float p[16];
        #pragma unroll
        for (int r = 0; r < 16; ++r) p[r] = __builtin_amdgcn_exp2f(S[r]);

        #pragma unroll
        for (int hh = 0; hh < 2; ++hh) {
            unsigned P0 = cvtpk(p[hh * 8 + 0], p[hh * 8 + 1]);
            unsigned P1 = cvtpk(p[hh * 8 + 2], p[hh * 8 + 3]);
            unsigned P2 = cvtpk(p[hh * 8 + 4], p[hh * 8 + 5]);
            unsigned P3 = cvtpk(p[hh * 8 + 6], p[hh * 8 + 7]);
            u32x2 s02 = __builtin_amdgcn_permlane32_swap(P0, P2, false, false);
            u32x2 s13 = __builtin_amdgcn_permlane32_swap(P1, P3, false, false);
            u32x4 bw = {s02[0], s13[0], s02[1], s13[1]};
            frag8 pf = __builtin_bit_cast(frag8, bw);
            Oacc = __builtin_amdgcn_mfma_f32_32x32x16_bf16(hh ? vb : va, pf, Oacc, 0, 0, 0);
        }
        kf2 = kn; va = van; vb = vbn; S = Sn;
    }

    if (dq) {
        // tail chunk 40: d 1280..1295 = S rows 0..7 (already in S), V in va
        float p[8];
        #pragma unroll
        for (int r = 0; r < 8; ++r) p[r] = __builtin_amdgcn_exp2f(S[r]);
        unsigned P0 = cvtpk(p[0], p[1]);
        unsigned P1 = cvtpk(p[2], p[3]);
        unsigned P2 = cvtpk(p[4], p[5]);
        unsigned P3 = cvtpk(p[6], p[7]);
        u32x2 s02 = __builtin_amdgcn_permlane32_swap(P0, P2, false, false);
        u32x2 s13 = __builtin_amdgcn_permlane32_swap(P1, P3, false, false);
        u32x4 bw = {s02[0], s13[0], s02[1], s13[1]};
        frag8 pf = __builtin_bit_cast(frag8, bw);
        Oacc = __builtin_amdgcn_mfma_f32_32x32x16_bf16(va, pf, Oacc, 0, 0, 0);
        #pragma unroll
        for (int r = 0; r < 8; ++r) Lc[qw][r][lane] = Oacc[r];
        Lc[qw][8][lane] = Oacc[8];
    }
    __syncthreads();
    if (dq == 0) {
        #pragma unroll
        for (int r = 0; r < 8; ++r) Oacc[r] += Lc[qw][r][lane];
        float lsum = Oacc[8] + Lc[qw][8][lane];
        u32x2 lb = __builtin_amdgcn_permlane32_swap(__float_as_uint(lsum),
                                                    __float_as_uint(lsum), false, false);
        float inv = frcp(__uint_as_float(lb[0]));
        if (qtok < HW) {
            short* An = (short*)A + ((size_t)n * HW + qtok) * CH + head * 16;
            int2 pk0 = pack4(Oacc[0] * inv, Oacc[1] * inv, Oacc[2] * inv, Oacc[3] * inv);
            int2 pk1 = pack4(Oacc[4] * inv, Oacc[5] * inv, Oacc[6] * inv, Oacc[7] * inv);
            *(int2*)&An[hi * 4] = pk0;
            *(int2*)&An[8 + hi * 4] = pk1;
        }
    }
}

extern "C" void kernel_launch(void* const* d_in, const int* in_sizes, int n_in,
                              void* d_out, int out_size, void* d_ws, size_t ws_size,
                              hipStream_t stream) {
    char* ws = (char*)d_ws;
    bf16*  Wst  = (bf16*)(ws + 256);          // 327680 bf16
    float* Bst  = (float*)(ws + 655616);      // 768 f32
    bf16*  XT   = (bf16*)(ws + 1048576);      // channel-last [n][1296][128]
    bf16*  Zb   = XT + TT;
    bf16*  Qb   = Zb + TT;                    // head-grouped [n][8][1296][16]
    bf16*  Kb   = Qb + TT;
    bf16*  Vb   = Kb + TT;                    // channel-first [n][128][1296]
    bf16*  Ab   = Vb + TT;                    // ~17 MB total

    k_prep<<<1284, 256, 0, stream>>>(d_in[1], d_in[3], d_in[5], d_in[6], d_in[7],
                                     d_in[8], d_in[12], d_in[14], d_in[16],
                                     d_in[2], d_in[4], d_in[9], d_in[13], d_in[15], d_in[17],
                                     Wst, Bst);
    // n on blockIdx.x (gridDim.x == 8): linear wg id % 8 == n -> per-batch XCD locality
    k_inm<<<dim3(8, 41, 4), 256, 0, stream>>>(d_in[0], d_in[1], Wst, Bst, XT);
    k_cq<<<dim3(8, 41), 512, 0, stream>>>(XT, Wst + 16384, Bst + 128, Wst + 163840,
                                          Zb, Qb, Kb, Vb);
    k_attn<<<dim3(8, 11, 8), 512, 0, stream>>>(Qb, Kb, Vb, Ab);
    k_cell<<<dim3(8, 81), 256, 0, stream>>>(Zb, Ab, Wst + 212992, Bst + 256,
                                            Wst + 311296, Bst + 640, d_out, d_in[1]);
}

// Round 13
// 186.412 us; speedup vs baseline: 1.0160x; 1.0160x over previous
//
#include <hip/hip_runtime.h>
#include <hip/hip_bf16.h>
#include <math.h>

typedef __hip_bfloat16 bf16;
typedef __attribute__((ext_vector_type(8))) short frag8;
typedef __attribute__((ext_vector_type(4))) float f32x4;
typedef __attribute__((ext_vector_type(16))) float f32x16;
typedef __attribute__((ext_vector_type(2))) unsigned int u32x2;
typedef __attribute__((ext_vector_type(4))) unsigned int u32x4;

#define HW  1296
#define CH  128
#define TT  1327104   // 8 * 1296 * 128

__device__ __forceinline__ float b2f(bf16 v) { return __bfloat162float(v); }
__device__ __forceinline__ float bits2f(unsigned short u) {
    return __uint_as_float(((unsigned)u) << 16);
}
__device__ __forceinline__ float frcp(float x) { return __builtin_amdgcn_rcpf(x); }
__device__ __forceinline__ float fsigm(float x) { return frcp(1.0f + __expf(-x)); }
__device__ __forceinline__ float ftanh(float x) {
    float xc = fminf(15.0f, fmaxf(-15.0f, x));
    float e = __expf(2.0f * xc);
    return (e - 1.0f) * frcp(e + 1.0f);
}
// round-half-up f32->bf16 pair pack: 2 adds + 1 v_perm
__device__ __forceinline__ int packrh(float a, float b) {
    unsigned ua = __float_as_uint(a) + 0x8000u;
    unsigned ub = __float_as_uint(b) + 0x8000u;
    return (int)__builtin_amdgcn_perm(ub, ua, 0x07060302);
}
__device__ __forceinline__ int2 pack4(float a, float b, float c, float d) {
    int2 r; r.x = packrh(a, b); r.y = packrh(c, d); return r;
}
// packed RNE f32 pair -> bf16x2 in one VALU op
__device__ __forceinline__ unsigned cvtpk(float a, float b) {
    unsigned r;
    asm("v_cvt_pk_bf16_f32 %0, %1, %2" : "=v"(r) : "v"(a), "v"(b));
    return r;
}

// inline wave-uniform dtype detection (256 probe elems of w_in)
__device__ __forceinline__ int detect_f32(const void* w) {
    const short4* p = (const short4*)w;
    short4 v = p[threadIdx.x & 63];
    int bad = 0;
    #pragma unroll
    for (int j = 0; j < 4; ++j) {
        float f = bits2f(((const unsigned short*)&v)[j]);
        if (!(fabsf(f) <= 100.0f)) bad = 1;   // catches NaN/Inf too
    }
    return __any(bad) ? 1 : 0;
}

// ---------------- weight prep ----------------
// Wst (bf16): w_in[128o][128i]@0 | wconvT[9tap][128o][128r]@16384 |
//   wqkv[384o][128i]@163840 | wg[3][128o][256k]@212992 | wout[128o][128i]@311296
// Bst f32[768]: in@0 conv@128 i@256 g@384 o@512 out@640
// Pad bf16[4096]: [0,2048) zeros | [2048,4096) ones — address-select targets so
// NO kernel ever does `cond ? load : constant` (the v_cndmask consuming a load
// result forces an immediate s_waitcnt per load — the 12-round serialization).
// wq rows pre-scaled by log2(e) so attention uses exp2 directly.
__global__ __launch_bounds__(256) void k_prep(
    const void* w_in, const void* w_conv, const void* wq, const void* wk, const void* wv,
    const void* w_i, const void* w_g, const void* w_o, const void* w_out,
    const void* b_in, const void* b_conv, const void* b_i, const void* b_g,
    const void* b_o, const void* b_out,
    bf16* __restrict__ Wdst, float* __restrict__ Bdst, bf16* __restrict__ Pad)
{
    int idx = blockIdx.x * 256 + threadIdx.x;
    const int f = detect_f32(w_in);
    if (idx < 327680) {
        const void* src; int si;
        if (idx < 16384)       { src = w_in; si = idx; }   // native [o][i]
        else if (idx < 163840) { int j = idx - 16384; int tap = j >> 14, rem = j & 16383;
                                 int o = rem >> 7, r = rem & 127;
                                 src = w_conv; si = o * 2304 + r * 9 + tap; }
        else if (idx < 212992) { int j = idx - 163840; int o = j >> 7, i = j & 127;
                                 int ws_ = o >> 7;
                                 src = ws_ == 0 ? wq : ws_ == 1 ? wk : wv;
                                 si = (o & 127) * 128 + i; }
        else if (idx < 311296) { int j = idx - 212992; int g = j >> 15, rem = j & 32767;
                                 int o = rem >> 8, k = rem & 255;
                                 src = g == 0 ? w_i : g == 1 ? w_g : w_o; si = o * 256 + k; }
        else                   { int j = idx - 311296; int o = j >> 7, i = j & 127;
                                 src = w_out; si = o * 128 + i; }
        float v = f ? ((const float*)src)[si] : b2f(((const bf16*)src)[si]);
        if (idx >= 163840 && idx < 180224) v *= 1.4426950408889634f;  // wq * log2(e)
        Wdst[idx] = __float2bfloat16(v);
    } else if (idx < 328448) {
        int j = idx - 327680; int b = j >> 7, e = j & 127;
        const void* src = b == 0 ? b_in : b == 1 ? b_conv : b == 2 ? b_i
                        : b == 3 ? b_g : b == 4 ? b_o : b_out;
        Bdst[j] = f ? ((const float*)src)[e] : b2f(((const bf16*)src)[e]);
    } else if (idx < 332544) {
        int j = idx - 328448;
        Pad[j] = __float2bfloat16(j < 2048 ? 0.0f : 1.0f);
    }
}

// ---------------- k_inm: fused transpose + MFMA GEMM + tanh ----------------
// grid (8 n, 41 ptile, 4 otile) — n on blockIdx.x => per-batch XCD locality.
// Staging loads are ADDRESS-clamped (no value select): OOB p rows hold valid
// x data from the clamped row; they feed only discarded output columns.
__global__ __launch_bounds__(256) void k_inm(const void* __restrict__ x,
                                             const void* __restrict__ wraw,
                                             const bf16* __restrict__ Wm,   // [o][i]
                                             const float* __restrict__ bias,
                                             bf16* __restrict__ XT) {
    __shared__ short Xl[32][132];
    const int tid = threadIdx.x, wave = tid >> 6, lane = tid & 63;
    const int quad = lane >> 4, l16 = lane & 15;
    const int n = blockIdx.x;
    const int pbase = blockIdx.y * 32;
    const int obase = blockIdx.z * 32 + (wave & 1) * 16;
    const int pstrip = (wave >> 1) * 16;
    const int f = detect_f32(wraw);

    // weight frags are LDS-independent: issue up front (overlap staging+barrier)
    frag8 WF[4];
    #pragma unroll
    for (int kc = 0; kc < 4; ++kc)
        WF[kc] = *(const frag8*)&Wm[(obase + l16) * CH + kc * 32 + quad * 8];

    #pragma unroll
    for (int rep = 0; rep < 4; ++rep) {
        int u = tid + rep * 256;
        int i = u >> 3;
        int p4 = (u & 7) * 4;
        int p = pbase + p4;
        int pc = p < HW ? p : HW - 4;     // address clamp (4-aligned, in bounds)
        size_t gi = (size_t)n * CH * HW + (size_t)i * HW + pc;
        short4 s;
        if (f) {
            float4 fv = *(const float4*)((const float*)x + gi);
            int2 pk = pack4(fv.x, fv.y, fv.z, fv.w);
            s = *(short4*)&pk;
        } else {
            s = *(const short4*)((const bf16*)x + gi);
        }
        Xl[p4 + 0][i] = s.x; Xl[p4 + 1][i] = s.y;
        Xl[p4 + 2][i] = s.z; Xl[p4 + 3][i] = s.w;
    }
    __syncthreads();

    const int pl = pstrip + l16;
    f32x4 acc = {0.f, 0.f, 0.f, 0.f};
    #pragma unroll
    for (int kc = 0; kc < 4; ++kc) {
        int k = kc * 32 + quad * 8;
        short4 b0 = *(const short4*)&Xl[pl][k];
        short4 b1 = *(const short4*)&Xl[pl][k + 4];
        frag8 bf = {b0.x, b0.y, b0.z, b0.w, b1.x, b1.y, b1.z, b1.w};
        acc = __builtin_amdgcn_mfma_f32_16x16x32_bf16(WF[kc], bf, acc, 0, 0, 0);
    }

    int p = pbase + pstrip + l16;
    if (p < HW) {
        int og = obase + quad * 4;
        int2 pk = pack4(ftanh(acc[0] + bias[og + 0]), ftanh(acc[1] + bias[og + 1]),
                        ftanh(acc[2] + bias[og + 2]), ftanh(acc[3] + bias[og + 3]));
        *(int2*)((short*)XT + ((size_t)n * HW + p) * CH + og) = pk;
    }
}

// ---------------- k_cq: FUSED 3x3 conv (tap-split x2) + QKV projection ----------------
// grid (8 n, 41 ptile), 512 threads = 8 waves (r9-validated geometry, 43.8us).
// NEW: halo-OOB activation loads use ADDRESS select to the zero-row Pad
// (unconditional loads, zero contribution preserved) — removes the per-load
// cndmask+waitcnt serialization that r11/r12 proved schedule-invariant.
__global__ __launch_bounds__(512) void k_cq(
    const bf16* __restrict__ XT, const bf16* __restrict__ Wc,
    const float* __restrict__ bc, const bf16* __restrict__ Wqkv,
    const bf16* __restrict__ Pad,
    bf16* __restrict__ Zb, bf16* __restrict__ Qb, bf16* __restrict__ Kb,
    bf16* __restrict__ Vb)
{
    __shared__ short Zl[32][136];        // 8.7 KB
    __shared__ float Rd[4][4][4][64];    // 16 KB: [o4][of*2+pt][reg][lane]
    const int tid = threadIdx.x, w = tid >> 6, lane = tid & 63;
    const int quad = lane >> 4, l16 = lane & 15;
    const int n = blockIdx.x;
    const int pbase = blockIdx.y * 32;
    const bf16* actn = XT + (size_t)n * HW * CH;

    // ---- conv phase: wave (o4, tg); 32o x 32p x {taps 0-4 | 5-8} ----
    const int o4 = w & 3, tg = w >> 2;
    const int obase = o4 * 32;
    const int p1 = pbase + l16, p2 = pbase + 16 + l16;
    const bool p1ok = p1 < HW, p2ok = p2 < HW;
    const int h1 = p1 / 36, w1 = p1 - h1 * 36;
    const int h2 = p2 / 36, w2 = p2 - h2 * 36;
    const bf16* zrow = Pad + quad * 8;   // zero row (per-quad column offset)

    f32x4 acc[2][2];   // [of][pt]
    #pragma unroll
    for (int of = 0; of < 2; ++of) {
        acc[of][0] = (f32x4){0.f, 0.f, 0.f, 0.f};
        acc[of][1] = (f32x4){0.f, 0.f, 0.f, 0.f};
    }

    const int tap0 = tg ? 5 : 0, tap1 = tg ? 9 : 5;
    for (int tap = tap0; tap < tap1; ++tap) {
        const int dy = tap / 3 - 1, dx = tap - (tap / 3) * 3 - 1;
        const bool ok1 = p1ok && (unsigned)(h1 + dy) < 36u && (unsigned)(w1 + dx) < 36u;
        const bool ok2 = p2ok && (unsigned)(h2 + dy) < 36u && (unsigned)(w2 + dx) < 36u;
        const int sh = dy * 36 + dx;
        // ADDRESS select (computed pre-issue) — loads below are unconditional
        const bf16* a1 = ok1 ? actn + (size_t)(p1 + sh) * CH + quad * 8 : zrow;
        const bf16* a2 = ok2 ? actn + (size_t)(p2 + sh) * CH + quad * 8 : zrow;
        const bf16* wp0 = Wc + tap * 16384 + (obase + l16) * CH + quad * 8;
        const bf16* wp1 = Wc + tap * 16384 + (obase + 16 + l16) * CH + quad * 8;
        frag8 A1[4], A2[4], W0[4], W1[4];
        #pragma unroll
        for (int kc = 0; kc < 4; ++kc) {
            A1[kc] = *(const frag8*)&a1[kc * 32];
            A2[kc] = *(const frag8*)&a2[kc * 32];
            W0[kc] = *(const frag8*)&wp0[kc * 32];
            W1[kc] = *(const frag8*)&wp1[kc * 32];
        }
        #pragma unroll
        for (int kc = 0; kc < 4; ++kc) {
            acc[0][0] = __builtin_amdgcn_mfma_f32_16x16x32_bf16(W0[kc], A1[kc], acc[0][0], 0, 0, 0);
            acc[0][1] = __builtin_amdgcn_mfma_f32_16x16x32_bf16(W0[kc], A2[kc], acc[0][1], 0, 0, 0);
            acc[1][0] = __builtin_amdgcn_mfma_f32_16x16x32_bf16(W1[kc], A1[kc], acc[1][0], 0, 0, 0);
            acc[1][1] = __builtin_amdgcn_mfma_f32_16x16x32_bf16(W1[kc], A2[kc], acc[1][1], 0, 0, 0);
        }
    }

    // tg=1 publishes partials; tg=0 reduces + epilogue
    if (tg == 1) {
        #pragma unroll
        for (int of = 0; of < 2; ++of)
            #pragma unroll
            for (int pt = 0; pt < 2; ++pt)
                #pragma unroll
                for (int r = 0; r < 4; ++r)
                    Rd[o4][of * 2 + pt][r][lane] = acc[of][pt][r];
    }
    __syncthreads();
    if (tg == 0) {
        #pragma unroll
        for (int of = 0; of < 2; ++of) {
            #pragma unroll
            for (int pt = 0; pt < 2; ++pt) {
                #pragma unroll
                for (int r = 0; r < 4; ++r)
                    acc[of][pt][r] += Rd[o4][of * 2 + pt][r][lane];
                int og = obase + of * 16 + quad * 4;
                int pl = pt * 16 + l16;
                int p = pbase + pl;
                int2 pk = pack4(acc[of][pt][0] + bc[og + 0], acc[of][pt][1] + bc[og + 1],
                                acc[of][pt][2] + bc[og + 2], acc[of][pt][3] + bc[og + 3]);
                *(int2*)&Zl[pl][og] = pk;
                if (p < HW)
                    *(int2*)((short*)Zb + ((size_t)n * HW + p) * CH + og) = pk;
            }
        }
    }
    __syncthreads();

    // ---- qkv phase (verified r8/r9 scheme; LDS reads unconditional) ----
    for (int ot = w; ot < 12; ot += 8) {
        const bool vt = (ot >= 8);          // wave-uniform
        const int ob = ot * 32;
        frag8 B1[4], B2[4], W0a[4], W1a[4];
        #pragma unroll
        for (int kc = 0; kc < 4; ++kc) {
            int ko = kc * 32 + quad * 8;
            B1[kc]  = *(const frag8*)&Zl[l16][ko];
            B2[kc]  = *(const frag8*)&Zl[16 + l16][ko];
            W0a[kc] = *(const frag8*)&Wqkv[(size_t)(ob + l16) * CH + ko];
            W1a[kc] = *(const frag8*)&Wqkv[(size_t)(ob + 16 + l16) * CH + ko];
        }

        f32x4 qacc[2][2];   // [of][pt]
        #pragma unroll
        for (int of = 0; of < 2; ++of) {
            qacc[of][0] = (f32x4){0.f, 0.f, 0.f, 0.f};
            qacc[of][1] = (f32x4){0.f, 0.f, 0.f, 0.f};
        }
        #pragma unroll
        for (int kc = 0; kc < 4; ++kc) {
            if (vt) {
                qacc[0][0] = __builtin_amdgcn_mfma_f32_16x16x32_bf16(B1[kc], W0a[kc], qacc[0][0], 0, 0, 0);
                qacc[0][1] = __builtin_amdgcn_mfma_f32_16x16x32_bf16(B2[kc], W0a[kc], qacc[0][1], 0, 0, 0);
                qacc[1][0] = __builtin_amdgcn_mfma_f32_16x16x32_bf16(B1[kc], W1a[kc], qacc[1][0], 0, 0, 0);
                qacc[1][1] = __builtin_amdgcn_mfma_f32_16x16x32_bf16(B2[kc], W1a[kc], qacc[1][1], 0, 0, 0);
            } else {
                qacc[0][0] = __builtin_amdgcn_mfma_f32_16x16x32_bf16(W0a[kc], B1[kc], qacc[0][0], 0, 0, 0);
                qacc[0][1] = __builtin_amdgcn_mfma_f32_16x16x32_bf16(W0a[kc], B2[kc], qacc[0][1], 0, 0, 0);
                qacc[1][0] = __builtin_amdgcn_mfma_f32_16x16x32_bf16(W1a[kc], B1[kc], qacc[1][0], 0, 0, 0);
                qacc[1][1] = __builtin_amdgcn_mfma_f32_16x16x32_bf16(W1a[kc], B2[kc], qacc[1][1], 0, 0, 0);
            }
        }

        if (vt) {
            #pragma unroll
            for (int of = 0; of < 2; ++of) {
                int ov = ob + of * 16 - 256 + l16;
                #pragma unroll
                for (int pt = 0; pt < 2; ++pt) {
                    int p4 = pbase + pt * 16 + quad * 4;
                    if (p4 >= HW) continue;
                    int2 pk = pack4(qacc[of][pt][0], qacc[of][pt][1], qacc[of][pt][2], qacc[of][pt][3]);
                    *(int2*)((short*)Vb + ((size_t)n * CH + ov) * HW + p4) = pk;
                }
            }
        } else {
            #pragma unroll
            for (int of = 0; of < 2; ++of) {
                int ogq = ob + of * 16 + quad * 4;
                int which = ogq >> 7, ol = ogq & 127;
                bf16* dst = which == 0 ? Qb : Kb;
                #pragma unroll
                for (int pt = 0; pt < 2; ++pt) {
                    int p = pbase + pt * 16 + l16;
                    if (p >= HW) continue;
                    size_t di = (((size_t)n * 8 + (ol >> 4)) * HW + p) * 16 + (ol & 15);
                    int2 pk = pack4(qacc[of][pt][0], qacc[of][pt][1], qacc[of][pt][2], qacc[of][pt][3]);
                    *(int2*)((short*)dst + di) = pk;
                }
            }
        }
    }
}

// ---------------- k_cell: gates GEMM + LSTM cell + fused out-projection ----------------
// grid (8 n, 81 ptile) — 81*16 = 1296 exactly, no p guards; all loads already
// unconditional (r9 version, best measured).
__global__ __launch_bounds__(256) void k_cell(
    const bf16* __restrict__ Zb, const bf16* __restrict__ Ab,
    const bf16* __restrict__ Wg, const float* __restrict__ bg,
    const bf16* __restrict__ Wo, const float* __restrict__ bo,
    void* __restrict__ out, const void* __restrict__ wraw)
{
    __shared__ short Hl[16][136];   // row stride 272B
    const int tid = threadIdx.x, w = tid >> 6, lane = tid & 63;
    const int quad = lane >> 4, l16 = lane & 15;
    const int n = blockIdx.x;
    const int pbase = blockIdx.y * 16;
    const int f32f = detect_f32(wraw);
    const bf16* zn = Zb + (size_t)n * HW * CH;
    const bf16* an = Ab + (size_t)n * HW * CH;

    const int obase = w * 32;
    const int p1 = pbase + l16;   // always < HW (81*16 == 1296)

    f32x4 acc[3][2];
    #pragma unroll
    for (int g = 0; g < 3; ++g) {
        acc[g][0] = (f32x4){0.f, 0.f, 0.f, 0.f};
        acc[g][1] = (f32x4){0.f, 0.f, 0.f, 0.f};
    }

    frag8 GB[2];
    frag8 GW[2][6];

    #define LOADG(KC, BUF)                                                           \
    {                                                                                \
        const bf16* src = ((KC) >= 4) ? an : zn;                                     \
        const int ko = ((KC) & 3) * 32 + quad * 8;                                   \
        GB[BUF] = *(const frag8*)&src[(size_t)p1 * CH + ko];                         \
        _Pragma("unroll")                                                            \
        for (int g = 0; g < 3; ++g) {                                                \
            _Pragma("unroll")                                                        \
            for (int of = 0; of < 2; ++of)                                           \
                GW[BUF][g * 2 + of] = *(const frag8*)&Wg[g * 32768 +                 \
                    (obase + of * 16 + l16) * 256 + (KC) * 32 + quad * 8];           \
        }                                                                            \
    }

    LOADG(0, 0);
    #pragma unroll
    for (int kc = 0; kc < 8; ++kc) {
        const int cur = kc & 1;
        if (kc < 7) LOADG(kc + 1, cur ^ 1);
        #pragma unroll
        for (int g = 0; g < 3; ++g) {
            #pragma unroll
            for (int of = 0; of < 2; ++of)
                acc[g][of] = __builtin_amdgcn_mfma_f32_16x16x32_bf16(
                    GW[cur][g * 2 + of], GB[cur], acc[g][of], 0, 0, 0);
        }
    }
    #undef LOADG

    // cell nonlinearity -> LDS h tile (C layout: row o = quad*4+r, col p = l16)
    #pragma unroll
    for (int of = 0; of < 2; ++of) {
        int og = obase + of * 16 + quad * 4;
        float hv[4];
        #pragma unroll
        for (int r = 0; r < 4; ++r) {
            int o = og + r;
            float iv = fsigm(acc[0][of][r] + bg[o]);
            float gv = ftanh(acc[1][of][r] + bg[128 + o]);
            float ov = fsigm(acc[2][of][r] + bg[256 + o]);
            hv[r] = ov * ftanh(iv * gv);
        }
        *(int2*)&Hl[l16][og] = pack4(hv[0], hv[1], hv[2], hv[3]);
    }

    // out-phase weight frags: LDS-independent, issue before the barrier
    frag8 OW[2][4];
    #pragma unroll
    for (int of = 0; of < 2; ++of)
        #pragma unroll
        for (int kc = 0; kc < 4; ++kc)
            OW[of][kc] = *(const frag8*)&Wo[(size_t)(obase + of * 16 + l16) * CH
                                            + kc * 32 + quad * 8];
    __syncthreads();

    f32x4 oc[2];
    oc[0] = (f32x4){0.f, 0.f, 0.f, 0.f};
    oc[1] = (f32x4){0.f, 0.f, 0.f, 0.f};
    #pragma unroll
    for (int kc = 0; kc < 4; ++kc) {
        int k = kc * 32 + quad * 8;
        short4 h0 = *(const short4*)&Hl[l16][k];
        short4 h1 = *(const short4*)&Hl[l16][k + 4];
        frag8 af = {h0.x, h0.y, h0.z, h0.w, h1.x, h1.y, h1.z, h1.w};
        #pragma unroll
        for (int of = 0; of < 2; ++of)
            oc[of] = __builtin_amdgcn_mfma_f32_16x16x32_bf16(af, OW[of][kc], oc[of], 0, 0, 0);
    }
    int p4 = pbase + quad * 4;
    #pragma unroll
    for (int of = 0; of < 2; ++of) {
        int o = obase + of * 16 + l16;
        float bv = bo[o];
        size_t di = ((size_t)n * CH + o) * HW + p4;
        if (f32f) {
            float4 fv = {oc[of][0] + bv, oc[of][1] + bv, oc[of][2] + bv, oc[of][3] + bv};
            *(float4*)&((float*)out)[di] = fv;
        } else {
            int2 pk = pack4(oc[of][0] + bv, oc[of][1] + bv, oc[of][2] + bv, oc[of][3] + bv);
            *(int2*)&((short*)out)[di] = pk;
        }
    }
}

// ---------------- MFMA flash attention v8: 32x32x16, d-split x2, addr-select ----------------
// grid (8 n, 11 qtile, 8 head), 512 threads = 8 waves: qw = w&3 (32 q each),
// dq = w>>2 (d-halves). Partial O/L over disjoint d-ranges combine additively.
// NEW: V fill rows come from the Pad ones/zero buffers via ADDRESS select
// (was `vload ? load : vfill` — a per-iteration cndmask+waitcnt, x60/wave);
// qf is address-clamped. All loads now unconditional.
// S layout (m74/m101): col=q=lane&31, row=d_local=(r&3)+8*(r>>2)+4*(lane>>5).
// lsum free: V A-operand row c==16 all-ones -> Oacc[8] = sum_d P[d][q].
__global__ __launch_bounds__(512) void k_attn(const bf16* __restrict__ Qg,
                                              const bf16* __restrict__ Kg,
                                              const bf16* __restrict__ Vcf,
                                              const bf16* __restrict__ Pad,
                                              bf16* __restrict__ A) {
    __shared__ float Lc[4][9][64];   // [qw][acc reg 0..7 + lsum][lane]

    const int tid = threadIdx.x;
    const int w = tid >> 6, lane = tid & 63;
    const int l32 = lane & 31, hi = lane >> 5;
    const int qw = w & 3, dq = w >> 2;
    const int n = blockIdx.x;
    const int head = blockIdx.z;
    const int qb = blockIdx.y * 128 + qw * 32;
    const int qtok = qb + l32;

    const short* Qh = (const short*)Qg + ((size_t)(n * 8 + head)) * HW * 16;
    const short* Kh = (const short*)Kg + ((size_t)(n * 8 + head)) * HW * 16;
    const short* Vh = (const short*)Vcf + ((size_t)n * CH + head * 16) * HW;

    // qf: address clamp (OOB q lanes read token 0; columns discarded at store)
    frag8 qf = *(const frag8*)&Qh[(size_t)(qtok < HW ? qtok : 0) * 16 + hi * 8];

    // V row pointer: real row for c<16; ones row for c==16 (lsum); zeros above.
    // Pad[0..2048)=0, Pad[2048..4096)=1.0 — max read index ~1312+15 < 2048. 
    const short* Vrow = (l32 < 16) ? Vh + (size_t)l32 * HW
                      : (const short*)(Pad + (l32 == 16 ? 2048 : 0));

    const f32x16 zero16 = {};
    f32x16 Oacc = {};

    auto KLD = [&](int dd) -> frag8 {
        return *(const frag8*)&Kh[(size_t)(dd + l32) * 16 + hi * 8];
    };
    auto VLD = [&](int dd) -> frag8 {
        return *(const frag8*)&Vrow[dd + hi * 8];
    };

    const int c0 = dq ? 20 : 0;
    frag8 kf  = KLD(c0 * 32);
    frag8 kf2 = KLD(c0 * 32 + 32);
    frag8 va  = VLD(c0 * 32);
    frag8 vb  = VLD(c0 * 32 + 16);
    f32x16 S = __builtin_amdgcn_mfma_f32_32x32x16_bf16(kf, qf, zero16, 0, 0, 0);

    for (int it = 0; it < 20; ++it) {
        const int d0 = (c0 + it) * 32;
        frag8 kn  = KLD(d0 + 64);
        frag8 van = VLD(d0 + 32);
        frag8 vbn = VLD(d0 + 48);
        f32x16 Sn = __builtin_amdgcn_mfma_f32_32x32x16_bf16(kf2, qf, zero16, 0, 0, 0);

        float p[16];
        #pragma unroll
        for (int r = 0; r < 16; ++r) p[r] = __builtin_amdgcn_exp2f(S[r]);

        #pragma unroll
        for (int hh = 0; hh < 2; ++hh) {
            unsigned P0 = cvtpk(p[hh * 8 + 0], p[hh * 8 + 1]);
            unsigned P1 = cvtpk(p[hh * 8 + 2], p[hh * 8 + 3]);
            unsigned P2 = cvtpk(p[hh * 8 + 4], p[hh * 8 + 5]);
            unsigned P3 = cvtpk(p[hh * 8 + 6], p[hh * 8 + 7]);
            u32x2 s02 = __builtin_amdgcn_permlane32_swap(P0, P2, false, false);
            u32x2 s13 = __builtin_amdgcn_permlane32_swap(P1, P3, false, false);
            u32x4 bw = {s02[0], s13[0], s02[1], s13[1]};
            frag8 pf = __builtin_bit_cast(frag8, bw);
            Oacc = __builtin_amdgcn_mfma_f32_32x32x16_bf16(hh ? vb : va, pf, Oacc, 0, 0, 0);
        }
        kf2 = kn; va = van; vb = vbn; S = Sn;
    }

    if (dq) {
        // tail chunk 40: d 1280..1295 = S rows 0..7 (already in S), V in va
        float p[8];
        #pragma unroll
        for (int r = 0; r < 8; ++r) p[r] = __builtin_amdgcn_exp2f(S[r]);
        unsigned P0 = cvtpk(p[0], p[1]);
        unsigned P1 = cvtpk(p[2], p[3]);
        unsigned P2 = cvtpk(p[4], p[5]);
        unsigned P3 = cvtpk(p[6], p[7]);
        u32x2 s02 = __builtin_amdgcn_permlane32_swap(P0, P2, false, false);
        u32x2 s13 = __builtin_amdgcn_permlane32_swap(P1, P3, false, false);
        u32x4 bw = {s02[0], s13[0], s02[1], s13[1]};
        frag8 pf = __builtin_bit_cast(frag8, bw);
        Oacc = __builtin_amdgcn_mfma_f32_32x32x16_bf16(va, pf, Oacc, 0, 0, 0);
        #pragma unroll
        for (int r = 0; r < 8; ++r) Lc[qw][r][lane] = Oacc[r];
        Lc[qw][8][lane] = Oacc[8];
    }
    __syncthreads();
    if (dq == 0) {
        #pragma unroll
        for (int r = 0; r < 8; ++r) Oacc[r] += Lc[qw][r][lane];
        float lsum = Oacc[8] + Lc[qw][8][lane];
        u32x2 lb = __builtin_amdgcn_permlane32_swap(__float_as_uint(lsum),
                                                    __float_as_uint(lsum), false, false);
        float inv = frcp(__uint_as_float(lb[0]));
        if (qtok < HW) {
            short* An = (short*)A + ((size_t)n * HW + qtok) * CH + head * 16;
            int2 pk0 = pack4(Oacc[0] * inv, Oacc[1] * inv, Oacc[2] * inv, Oacc[3] * inv);
            int2 pk1 = pack4(Oacc[4] * inv, Oacc[5] * inv, Oacc[6] * inv, Oacc[7] * inv);
            *(int2*)&An[hi * 4] = pk0;
            *(int2*)&An[8 + hi * 4] = pk1;
        }
    }
}

extern "C" void kernel_launch(void* const* d_in, const int* in_sizes, int n_in,
                              void* d_out, int out_size, void* d_ws, size_t ws_size,
                              hipStream_t stream) {
    char* ws = (char*)d_ws;
    bf16*  Wst  = (bf16*)(ws + 256);          // 327680 bf16
    float* Bst  = (float*)(ws + 655616);      // 768 f32
    bf16*  Pad  = (bf16*)(ws + 786432);       // 2048 zeros | 2048 ones
    bf16*  XT   = (bf16*)(ws + 1048576);      // channel-last [n][1296][128]
    bf16*  Zb   = XT + TT;
    bf16*  Qb   = Zb + TT;                    // head-grouped [n][8][1296][16]
    bf16*  Kb   = Qb + TT;
    bf16*  Vb   = Kb + TT;                    // channel-first [n][128][1296]
    bf16*  Ab   = Vb + TT;                    // ~17 MB total

    k_prep<<<1300, 256, 0, stream>>>(d_in[1], d_in[3], d_in[5], d_in[6], d_in[7],
                                     d_in[8], d_in[12], d_in[14], d_in[16],
                                     d_in[2], d_in[4], d_in[9], d_in[13], d_in[15], d_in[17],
                                     Wst, Bst, Pad);
    // n on blockIdx.x (gridDim.x == 8): linear wg id % 8 == n -> per-batch XCD locality
    k_inm<<<dim3(8, 41, 4), 256, 0, stream>>>(d_in[0], d_in[1], Wst, Bst, XT);
    k_cq<<<dim3(8, 41), 512, 0, stream>>>(XT, Wst + 16384, Bst + 128, Wst + 163840,
                                          Pad, Zb, Qb, Kb, Vb);
    k_attn<<<dim3(8, 11, 8), 512, 0, stream>>>(Qb, Kb, Vb, Pad, Ab);
    k_cell<<<dim3(8, 81), 256, 0, stream>>>(Zb, Ab, Wst + 212992, Bst + 256,
                                            Wst + 311296, Bst + 640, d_out, d_in[1]);
}

// Round 14
// 168.692 us; speedup vs baseline: 1.1228x; 1.1050x over previous
//
#include <hip/hip_runtime.h>
#include <hip/hip_bf16.h>
#include <math.h>

typedef __hip_bfloat16 bf16;
typedef __attribute__((ext_vector_type(8))) short frag8;
typedef __attribute__((ext_vector_type(4))) float f32x4;
typedef __attribute__((ext_vector_type(16))) float f32x16;
typedef __attribute__((ext_vector_type(2))) unsigned int u32x2;
typedef __attribute__((ext_vector_type(4))) unsigned int u32x4;

#define HW  1296
#define CH  128
#define TT  1327104   // 8 * 1296 * 128

__device__ __forceinline__ float b2f(bf16 v) { return __bfloat162float(v); }
__device__ __forceinline__ float bits2f(unsigned short u) {
    return __uint_as_float(((unsigned)u) << 16);
}
__device__ __forceinline__ float frcp(float x) { return __builtin_amdgcn_rcpf(x); }
__device__ __forceinline__ float fsigm(float x) { return frcp(1.0f + __expf(-x)); }
__device__ __forceinline__ float ftanh(float x) {
    float xc = fminf(15.0f, fmaxf(-15.0f, x));
    float e = __expf(2.0f * xc);
    return (e - 1.0f) * frcp(e + 1.0f);
}
// round-half-up f32->bf16 pair pack: 2 adds + 1 v_perm
__device__ __forceinline__ int packrh(float a, float b) {
    unsigned ua = __float_as_uint(a) + 0x8000u;
    unsigned ub = __float_as_uint(b) + 0x8000u;
    return (int)__builtin_amdgcn_perm(ub, ua, 0x07060302);
}
__device__ __forceinline__ int2 pack4(float a, float b, float c, float d) {
    int2 r; r.x = packrh(a, b); r.y = packrh(c, d); return r;
}
// packed RNE f32 pair -> bf16x2 in one VALU op
__device__ __forceinline__ unsigned cvtpk(float a, float b) {
    unsigned r;
    asm("v_cvt_pk_bf16_f32 %0, %1, %2" : "=v"(r) : "v"(a), "v"(b));
    return r;
}

// inline wave-uniform dtype detection (256 probe elems of w_in)
__device__ __forceinline__ int detect_f32(const void* w) {
    const short4* p = (const short4*)w;
    short4 v = p[threadIdx.x & 63];
    int bad = 0;
    #pragma unroll
    for (int j = 0; j < 4; ++j) {
        float f = bits2f(((const unsigned short*)&v)[j]);
        if (!(fabsf(f) <= 100.0f)) bad = 1;   // catches NaN/Inf too
    }
    return __any(bad) ? 1 : 0;
}

// ---------------- weight prep ----------------
// Wst (bf16): w_in[128o][128i]@0 | wconvT[9tap][128o][128r]@16384 |
//   wqkv[384o][128i]@163840 | wg[3][128o][256k]@212992 | wout[128o][128i]@311296
// Bst f32[768]: in@0 conv@128 i@256 g@384 o@512 out@640
// Pad bf16[4096]: [0,2048) zeros | [2048,4096) ones — address-select targets.
// wq rows pre-scaled by log2(e) so attention uses exp2 directly.
__global__ __launch_bounds__(256) void k_prep(
    const void* w_in, const void* w_conv, const void* wq, const void* wk, const void* wv,
    const void* w_i, const void* w_g, const void* w_o, const void* w_out,
    const void* b_in, const void* b_conv, const void* b_i, const void* b_g,
    const void* b_o, const void* b_out,
    bf16* __restrict__ Wdst, float* __restrict__ Bdst, bf16* __restrict__ Pad)
{
    int idx = blockIdx.x * 256 + threadIdx.x;
    const int f = detect_f32(w_in);
    if (idx < 327680) {
        const void* src; int si;
        if (idx < 16384)       { src = w_in; si = idx; }   // native [o][i]
        else if (idx < 163840) { int j = idx - 16384; int tap = j >> 14, rem = j & 16383;
                                 int o = rem >> 7, r = rem & 127;
                                 src = w_conv; si = o * 2304 + r * 9 + tap; }
        else if (idx < 212992) { int j = idx - 163840; int o = j >> 7, i = j & 127;
                                 int ws_ = o >> 7;
                                 src = ws_ == 0 ? wq : ws_ == 1 ? wk : wv;
                                 si = (o & 127) * 128 + i; }
        else if (idx < 311296) { int j = idx - 212992; int g = j >> 15, rem = j & 32767;
                                 int o = rem >> 8, k = rem & 255;
                                 src = g == 0 ? w_i : g == 1 ? w_g : w_o; si = o * 256 + k; }
        else                   { int j = idx - 311296; int o = j >> 7, i = j & 127;
                                 src = w_out; si = o * 128 + i; }
        float v = f ? ((const float*)src)[si] : b2f(((const bf16*)src)[si]);
        if (idx >= 163840 && idx < 180224) v *= 1.4426950408889634f;  // wq * log2(e)
        Wdst[idx] = __float2bfloat16(v);
    } else if (idx < 328448) {
        int j = idx - 327680; int b = j >> 7, e = j & 127;
        const void* src = b == 0 ? b_in : b == 1 ? b_conv : b == 2 ? b_i
                        : b == 3 ? b_g : b == 4 ? b_o : b_out;
        Bdst[j] = f ? ((const float*)src)[e] : b2f(((const bf16*)src)[e]);
    } else if (idx < 332544) {
        int j = idx - 328448;
        Pad[j] = __float2bfloat16(j < 2048 ? 0.0f : 1.0f);
    }
}

// ---------------- k_inm: fused transpose + MFMA GEMM + tanh ----------------
// grid (8 n, 41 ptile, 4 otile) — n on blockIdx.x => per-batch XCD locality.
__global__ __launch_bounds__(256) void k_inm(const void* __restrict__ x,
                                             const void* __restrict__ wraw,
                                             const bf16* __restrict__ Wm,   // [o][i]
                                             const float* __restrict__ bias,
                                             bf16* __restrict__ XT) {
    __shared__ short Xl[32][132];
    const int tid = threadIdx.x, wave = tid >> 6, lane = tid & 63;
    const int quad = lane >> 4, l16 = lane & 15;
    const int n = blockIdx.x;
    const int pbase = blockIdx.y * 32;
    const int obase = blockIdx.z * 32 + (wave & 1) * 16;
    const int pstrip = (wave >> 1) * 16;
    const int f = detect_f32(wraw);

    // weight frags are LDS-independent: issue up front (overlap staging+barrier)
    frag8 WF[4];
    #pragma unroll
    for (int kc = 0; kc < 4; ++kc)
        WF[kc] = *(const frag8*)&Wm[(obase + l16) * CH + kc * 32 + quad * 8];

    #pragma unroll
    for (int rep = 0; rep < 4; ++rep) {
        int u = tid + rep * 256;
        int i = u >> 3;
        int p4 = (u & 7) * 4;
        int p = pbase + p4;
        int pc = p < HW ? p : HW - 4;     // address clamp (4-aligned, in bounds)
        size_t gi = (size_t)n * CH * HW + (size_t)i * HW + pc;
        short4 s;
        if (f) {
            float4 fv = *(const float4*)((const float*)x + gi);
            int2 pk = pack4(fv.x, fv.y, fv.z, fv.w);
            s = *(short4*)&pk;
        } else {
            s = *(const short4*)((const bf16*)x + gi);
        }
        Xl[p4 + 0][i] = s.x; Xl[p4 + 1][i] = s.y;
        Xl[p4 + 2][i] = s.z; Xl[p4 + 3][i] = s.w;
    }
    __syncthreads();

    const int pl = pstrip + l16;
    f32x4 acc = {0.f, 0.f, 0.f, 0.f};
    #pragma unroll
    for (int kc = 0; kc < 4; ++kc) {
        int k = kc * 32 + quad * 8;
        short4 b0 = *(const short4*)&Xl[pl][k];
        short4 b1 = *(const short4*)&Xl[pl][k + 4];
        frag8 bf = {b0.x, b0.y, b0.z, b0.w, b1.x, b1.y, b1.z, b1.w};
        acc = __builtin_amdgcn_mfma_f32_16x16x32_bf16(WF[kc], bf, acc, 0, 0, 0);
    }

    int p = pbase + pstrip + l16;
    if (p < HW) {
        int og = obase + quad * 4;
        int2 pk = pack4(ftanh(acc[0] + bias[og + 0]), ftanh(acc[1] + bias[og + 1]),
                        ftanh(acc[2] + bias[og + 2]), ftanh(acc[3] + bias[og + 3]));
        *(int2*)((short*)XT + ((size_t)n * HW + p) * CH + og) = pk;
    }
}

// ---------------- k_cq: FUSED 3x3 conv (LDS-STAGED activations) + QKV ----------------
// grid (8 n, 41 ptile), 512 threads = 8 waves, wave w = 16o x 32p, all 9 taps.
// r10-r13 proved per-load exposure is invariant to schedule/VGPR/conditionals:
// so change the MEMORY LEVEL instead. The 128-row halo tile (p in
// [pbase-37, pbase+90]) is staged ONCE into LDS via 4 batched coalesced loads
// per thread (one latency exposure, OOB rows sourced from Pad zeros via
// address select), then all 72 A-operand reads per wave come from LDS
// (~12cy ds_read, 272B padded rows = 2-way banks = free). Also kills the 9x
// halo re-read. OOB taps read LDS zero row 112 (address select). Weights
// remain global (L2-hot). Rd reduce + tap-split dropped (no longer needed).
__global__ __launch_bounds__(512) void k_cq(
    const bf16* __restrict__ XT, const bf16* __restrict__ Wc,
    const float* __restrict__ bc, const bf16* __restrict__ Wqkv,
    const bf16* __restrict__ Pad,
    bf16* __restrict__ Zb, bf16* __restrict__ Qb, bf16* __restrict__ Kb,
    bf16* __restrict__ Vb)
{
    __shared__ short Xs[128][136];   // 34 KB; row r = p = pbase-37+r; 112+ = zeros
    __shared__ short Zl[32][136];    // 8.7 KB
    const int tid = threadIdx.x, w = tid >> 6, lane = tid & 63;
    const int quad = lane >> 4, l16 = lane & 15;
    const int n = blockIdx.x;
    const int pbase = blockIdx.y * 32;
    const bf16* XTn = XT + (size_t)n * HW * CH;

    // ---- stage: 128 rows x 16 chunks(16B) = 2048 chunks, 4 per thread ----
    {
        frag8 st[4];
        int rowv[4], chv[4];
        #pragma unroll
        for (int i = 0; i < 4; ++i) {
            int ci = i * 512 + tid;
            int row = ci >> 4, ch = ci & 15;
            rowv[i] = row; chv[i] = ch;
            int p = pbase - 37 + row;
            const bf16* src = (row < 112 && (unsigned)p < (unsigned)HW)
                            ? &XTn[(size_t)p * CH + ch * 8] : &Pad[ch * 8];
            st[i] = *(const frag8*)src;
        }
        #pragma unroll
        for (int i = 0; i < 4; ++i)
            *(frag8*)&Xs[rowv[i]][chv[i] * 8] = st[i];
    }
    __syncthreads();

    // ---- conv: wave w owns o [w*16, w*16+16) x 32p, 9 taps from LDS ----
    const int obase = w * 16;
    const int p1 = pbase + l16, p2 = p1 + 16;
    const int h1 = p1 / 36, w1 = p1 - h1 * 36;
    const int h2 = p2 / 36, w2 = p2 - h2 * 36;
    const bool p1ok = p1 < HW, p2ok = p2 < HW;

    f32x4 acc[2];
    acc[0] = (f32x4){0.f, 0.f, 0.f, 0.f};
    acc[1] = (f32x4){0.f, 0.f, 0.f, 0.f};

    #pragma unroll
    for (int tap = 0; tap < 9; ++tap) {
        const int dy = tap / 3 - 1, dx = tap - (tap / 3) * 3 - 1;
        const bool ok1 = p1ok && (unsigned)(h1 + dy) < 36u && (unsigned)(w1 + dx) < 36u;
        const bool ok2 = p2ok && (unsigned)(h2 + dy) < 36u && (unsigned)(w2 + dx) < 36u;
        const int sh = dy * 36 + dx;
        const int r1 = ok1 ? 37 + l16 + sh : 112;        // LDS address select
        const int r2 = ok2 ? 53 + l16 + sh : 112;        // (zero row 112)
        const bf16* wp = Wc + tap * 16384 + (obase + l16) * CH + quad * 8;
        #pragma unroll
        for (int kc = 0; kc < 4; ++kc) {
            frag8 a1 = *(const frag8*)&Xs[r1][kc * 32 + quad * 8];
            frag8 a2 = *(const frag8*)&Xs[r2][kc * 32 + quad * 8];
            frag8 wf = *(const frag8*)&wp[kc * 32];
            acc[0] = __builtin_amdgcn_mfma_f32_16x16x32_bf16(wf, a1, acc[0], 0, 0, 0);
            acc[1] = __builtin_amdgcn_mfma_f32_16x16x32_bf16(wf, a2, acc[1], 0, 0, 0);
        }
    }

    // epilogue: z -> LDS Zl (always) + global Zb (guarded)
    const int og = obase + quad * 4;
    #pragma unroll
    for (int pt = 0; pt < 2; ++pt) {
        int pl = pt * 16 + l16;
        int p = pbase + pl;
        int2 pk = pack4(acc[pt][0] + bc[og + 0], acc[pt][1] + bc[og + 1],
                        acc[pt][2] + bc[og + 2], acc[pt][3] + bc[og + 3]);
        *(int2*)&Zl[pl][og] = pk;
        if (p < HW)
            *(int2*)((short*)Zb + ((size_t)n * HW + p) * CH + og) = pk;
    }
    __syncthreads();

    // ---- qkv phase (verified r8/r9 scheme) ----
    for (int ot = w; ot < 12; ot += 8) {
        const bool vt = (ot >= 8);          // wave-uniform
        const int ob = ot * 32;
        frag8 B1[4], B2[4], W0a[4], W1a[4];
        #pragma unroll
        for (int kc = 0; kc < 4; ++kc) {
            int ko = kc * 32 + quad * 8;
            B1[kc]  = *(const frag8*)&Zl[l16][ko];
            B2[kc]  = *(const frag8*)&Zl[16 + l16][ko];
            W0a[kc] = *(const frag8*)&Wqkv[(size_t)(ob + l16) * CH + ko];
            W1a[kc] = *(const frag8*)&Wqkv[(size_t)(ob + 16 + l16) * CH + ko];
        }

        f32x4 qacc[2][2];   // [of][pt]
        #pragma unroll
        for (int of = 0; of < 2; ++of) {
            qacc[of][0] = (f32x4){0.f, 0.f, 0.f, 0.f};
            qacc[of][1] = (f32x4){0.f, 0.f, 0.f, 0.f};
        }
        #pragma unroll
        for (int kc = 0; kc < 4; ++kc) {
            if (vt) {
                qacc[0][0] = __builtin_amdgcn_mfma_f32_16x16x32_bf16(B1[kc], W0a[kc], qacc[0][0], 0, 0, 0);
                qacc[0][1] = __builtin_amdgcn_mfma_f32_16x16x32_bf16(B2[kc], W0a[kc], qacc[0][1], 0, 0, 0);
                qacc[1][0] = __builtin_amdgcn_mfma_f32_16x16x32_bf16(B1[kc], W1a[kc], qacc[1][0], 0, 0, 0);
                qacc[1][1] = __builtin_amdgcn_mfma_f32_16x16x32_bf16(B2[kc], W1a[kc], qacc[1][1], 0, 0, 0);
            } else {
                qacc[0][0] = __builtin_amdgcn_mfma_f32_16x16x32_bf16(W0a[kc], B1[kc], qacc[0][0], 0, 0, 0);
                qacc[0][1] = __builtin_amdgcn_mfma_f32_16x16x32_bf16(W0a[kc], B2[kc], qacc[0][1], 0, 0, 0);
                qacc[1][0] = __builtin_amdgcn_mfma_f32_16x16x32_bf16(W1a[kc], B1[kc], qacc[1][0], 0, 0, 0);
                qacc[1][1] = __builtin_amdgcn_mfma_f32_16x16x32_bf16(W1a[kc], B2[kc], qacc[1][1], 0, 0, 0);
            }
        }

        if (vt) {
            #pragma unroll
            for (int of = 0; of < 2; ++of) {
                int ov = ob + of * 16 - 256 + l16;
                #pragma unroll
                for (int pt = 0; pt < 2; ++pt) {
                    int p4 = pbase + pt * 16 + quad * 4;
                    if (p4 >= HW) continue;
                    int2 pk = pack4(qacc[of][pt][0], qacc[of][pt][1], qacc[of][pt][2], qacc[of][pt][3]);
                    *(int2*)((short*)Vb + ((size_t)n * CH + ov) * HW + p4) = pk;
                }
            }
        } else {
            #pragma unroll
            for (int of = 0; of < 2; ++of) {
                int ogq = ob + of * 16 + quad * 4;
                int which = ogq >> 7, ol = ogq & 127;
                bf16* dst = which == 0 ? Qb : Kb;
                #pragma unroll
                for (int pt = 0; pt < 2; ++pt) {
                    int p = pbase + pt * 16 + l16;
                    if (p >= HW) continue;
                    size_t di = (((size_t)n * 8 + (ol >> 4)) * HW + p) * 16 + (ol & 15);
                    int2 pk = pack4(qacc[of][pt][0], qacc[of][pt][1], qacc[of][pt][2], qacc[of][pt][3]);
                    *(int2*)((short*)dst + di) = pk;
                }
            }
        }
    }
}

// ---------------- k_cell: gates GEMM + LSTM cell + fused out-projection ----------------
// grid (8 n, 81 ptile) — 81*16 = 1296 exactly, no p guards (r9 version).
__global__ __launch_bounds__(256) void k_cell(
    const bf16* __restrict__ Zb, const bf16* __restrict__ Ab,
    const bf16* __restrict__ Wg, const float* __restrict__ bg,
    const bf16* __restrict__ Wo, const float* __restrict__ bo,
    void* __restrict__ out, const void* __restrict__ wraw)
{
    __shared__ short Hl[16][136];   // row stride 272B
    const int tid = threadIdx.x, w = tid >> 6, lane = tid & 63;
    const int quad = lane >> 4, l16 = lane & 15;
    const int n = blockIdx.x;
    const int pbase = blockIdx.y * 16;
    const int f32f = detect_f32(wraw);
    const bf16* zn = Zb + (size_t)n * HW * CH;
    const bf16* an = Ab + (size_t)n * HW * CH;

    const int obase = w * 32;
    const int p1 = pbase + l16;   // always < HW (81*16 == 1296)

    f32x4 acc[3][2];
    #pragma unroll
    for (int g = 0; g < 3; ++g) {
        acc[g][0] = (f32x4){0.f, 0.f, 0.f, 0.f};
        acc[g][1] = (f32x4){0.f, 0.f, 0.f, 0.f};
    }

    frag8 GB[2];
    frag8 GW[2][6];

    #define LOADG(KC, BUF)                                                           \
    {                                                                                \
        const bf16* src = ((KC) >= 4) ? an : zn;                                     \
        const int ko = ((KC) & 3) * 32 + quad * 8;                                   \
        GB[BUF] = *(const frag8*)&src[(size_t)p1 * CH + ko];                         \
        _Pragma("unroll")                                                            \
        for (int g = 0; g < 3; ++g) {                                                \
            _Pragma("unroll")                                                        \
            for (int of = 0; of < 2; ++of)                                           \
                GW[BUF][g * 2 + of] = *(const frag8*)&Wg[g * 32768 +                 \
                    (obase + of * 16 + l16) * 256 + (KC) * 32 + quad * 8];           \
        }                                                                            \
    }

    LOADG(0, 0);
    #pragma unroll
    for (int kc = 0; kc < 8; ++kc) {
        const int cur = kc & 1;
        if (kc < 7) LOADG(kc + 1, cur ^ 1);
        #pragma unroll
        for (int g = 0; g < 3; ++g) {
            #pragma unroll
            for (int of = 0; of < 2; ++of)
                acc[g][of] = __builtin_amdgcn_mfma_f32_16x16x32_bf16(
                    GW[cur][g * 2 + of], GB[cur], acc[g][of], 0, 0, 0);
        }
    }
    #undef LOADG

    // cell nonlinearity -> LDS h tile (C layout: row o = quad*4+r, col p = l16)
    #pragma unroll
    for (int of = 0; of < 2; ++of) {
        int og = obase + of * 16 + quad * 4;
        float hv[4];
        #pragma unroll
        for (int r = 0; r < 4; ++r) {
            int o = og + r;
            float iv = fsigm(acc[0][of][r] + bg[o]);
            float gv = ftanh(acc[1][of][r] + bg[128 + o]);
            float ov = fsigm(acc[2][of][r] + bg[256 + o]);
            hv[r] = ov * ftanh(iv * gv);
        }
        *(int2*)&Hl[l16][og] = pack4(hv[0], hv[1], hv[2], hv[3]);
    }

    // out-phase weight frags: LDS-independent, issue before the barrier
    frag8 OW[2][4];
    #pragma unroll
    for (int of = 0; of < 2; ++of)
        #pragma unroll
        for (int kc = 0; kc < 4; ++kc)
            OW[of][kc] = *(const frag8*)&Wo[(size_t)(obase + of * 16 + l16) * CH
                                            + kc * 32 + quad * 8];
    __syncthreads();

    f32x4 oc[2];
    oc[0] = (f32x4){0.f, 0.f, 0.f, 0.f};
    oc[1] = (f32x4){0.f, 0.f, 0.f, 0.f};
    #pragma unroll
    for (int kc = 0; kc < 4; ++kc) {
        int k = kc * 32 + quad * 8;
        short4 h0 = *(const short4*)&Hl[l16][k];
        short4 h1 = *(const short4*)&Hl[l16][k + 4];
        frag8 af = {h0.x, h0.y, h0.z, h0.w, h1.x, h1.y, h1.z, h1.w};
        #pragma unroll
        for (int of = 0; of < 2; ++of)
            oc[of] = __builtin_amdgcn_mfma_f32_16x16x32_bf16(af, OW[of][kc], oc[of], 0, 0, 0);
    }
    int p4 = pbase + quad * 4;
    #pragma unroll
    for (int of = 0; of < 2; ++of) {
        int o = obase + of * 16 + l16;
        float bv = bo[o];
        size_t di = ((size_t)n * CH + o) * HW + p4;
        if (f32f) {
            float4 fv = {oc[of][0] + bv, oc[of][1] + bv, oc[of][2] + bv, oc[of][3] + bv};
            *(float4*)&((float*)out)[di] = fv;
        } else {
            int2 pk = pack4(oc[of][0] + bv, oc[of][1] + bv, oc[of][2] + bv, oc[of][3] + bv);
            *(int2*)&((short*)out)[di] = pk;
        }
    }
}

// ---------------- MFMA flash attention v8: 32x32x16, d-split x2, addr-select ----------------
// grid (8 n, 11 qtile, 8 head), 512 threads = 8 waves: qw = w&3 (32 q each),
// dq = w>>2 (d-halves). Partial O/L over disjoint d-ranges combine additively.
// V fill rows come from Pad ones/zero via ADDRESS select; qf address-clamped.
// S layout (m74/m101): col=q=lane&31, row=d_local=(r&3)+8*(r>>2)+4*(lane>>5).
// lsum free: V A-operand row c==16 all-ones -> Oacc[8] = sum_d P[d][q].
__global__ __launch_bounds__(512) void k_attn(const bf16* __restrict__ Qg,
                                              const bf16* __restrict__ Kg,
                                              const bf16* __restrict__ Vcf,
                                              const bf16* __restrict__ Pad,
                                              bf16* __restrict__ A) {
    __shared__ float Lc[4][9][64];   // [qw][acc reg 0..7 + lsum][lane]

    const int tid = threadIdx.x;
    const int w = tid >> 6, lane = tid & 63;
    const int l32 = lane & 31, hi = lane >> 5;
    const int qw = w & 3, dq = w >> 2;
    const int n = blockIdx.x;
    const int head = blockIdx.z;
    const int qb = blockIdx.y * 128 + qw * 32;
    const int qtok = qb + l32;

    const short* Qh = (const short*)Qg + ((size_t)(n * 8 + head)) * HW * 16;
    const short* Kh = (const short*)Kg + ((size_t)(n * 8 + head)) * HW * 16;
    const short* Vh = (const short*)Vcf + ((size_t)n * CH + head * 16) * HW;

    // qf: address clamp (OOB q lanes read token 0; columns discarded at store)
    frag8 qf = *(const frag8*)&Qh[(size_t)(qtok < HW ? qtok : 0) * 16 + hi * 8];

    // V row pointer: real row for c<16; ones row for c==16 (lsum); zeros above.
    const short* Vrow = (l32 < 16) ? Vh + (size_t)l32 * HW
                      : (const short*)(Pad + (l32 == 16 ? 2048 : 0));

    const f32x16 zero16 = {};
    f32x16 Oacc = {};

    auto KLD = [&](int dd) -> frag8 {
        return *(const frag8*)&Kh[(size_t)(dd + l32) * 16 + hi * 8];
    };
    auto VLD = [&](int dd) -> frag8 {
        return *(const frag8*)&Vrow[dd + hi * 8];
    };

    const int c0 = dq ? 20 : 0;
    frag8 kf  = KLD(c0 * 32);
    frag8 kf2 = KLD(c0 * 32 + 32);
    frag8 va  = VLD(c0 * 32);
    frag8 vb  = VLD(c0 * 32 + 16);
    f32x16 S = __builtin_amdgcn_mfma_f32_32x32x16_bf16(kf, qf, zero16, 0, 0, 0);

    for (int it = 0; it < 20; ++it) {
        const int d0 = (c0 + it) * 32;
        frag8 kn  = KLD(d0 + 64);
        frag8 van = VLD(d0 + 32);
        frag8 vbn = VLD(d0 + 48);
        f32x16 Sn = __builtin_amdgcn_mfma_f32_32x32x16_bf16(kf2, qf, zero16, 0, 0, 0);

        float p[16];
        #pragma unroll
        for (int r = 0; r < 16; ++r) p[r] = __builtin_amdgcn_exp2f(S[r]);

        #pragma unroll
        for (int hh = 0; hh < 2; ++hh) {
            unsigned P0 = cvtpk(p[hh * 8 + 0], p[hh * 8 + 1]);
            unsigned P1 = cvtpk(p[hh * 8 + 2], p[hh * 8 + 3]);
            unsigned P2 = cvtpk(p[hh * 8 + 4], p[hh * 8 + 5]);
            unsigned P3 = cvtpk(p[hh * 8 + 6], p[hh * 8 + 7]);
            u32x2 s02 = __builtin_amdgcn_permlane32_swap(P0, P2, false, false);
            u32x2 s13 = __builtin_amdgcn_permlane32_swap(P1, P3, false, false);
            u32x4 bw = {s02[0], s13[0], s02[1], s13[1]};
            frag8 pf = __builtin_bit_cast(frag8, bw);
            Oacc = __builtin_amdgcn_mfma_f32_32x32x16_bf16(hh ? vb : va, pf, Oacc, 0, 0, 0);
        }
        kf2 = kn; va = van; vb = vbn; S = Sn;
    }

    if (dq) {
        // tail chunk 40: d 1280..1295 = S rows 0..7 (already in S), V in va
        float p[8];
        #pragma unroll
        for (int r = 0; r < 8; ++r) p[r] = __builtin_amdgcn_exp2f(S[r]);
        unsigned P0 = cvtpk(p[0], p[1]);
        unsigned P1 = cvtpk(p[2], p[3]);
        unsigned P2 = cvtpk(p[4], p[5]);
        unsigned P3 = cvtpk(p[6], p[7]);
        u32x2 s02 = __builtin_amdgcn_permlane32_swap(P0, P2, false, false);
        u32x2 s13 = __builtin_amdgcn_permlane32_swap(P1, P3, false, false);
        u32x4 bw = {s02[0], s13[0], s02[1], s13[1]};
        frag8 pf = __builtin_bit_cast(frag8, bw);
        Oacc = __builtin_amdgcn_mfma_f32_32x32x16_bf16(va, pf, Oacc, 0, 0, 0);
        #pragma unroll
        for (int r = 0; r < 8; ++r) Lc[qw][r][lane] = Oacc[r];
        Lc[qw][8][lane] = Oacc[8];
    }
    __syncthreads();
    if (dq == 0) {
        #pragma unroll
        for (int r = 0; r < 8; ++r) Oacc[r] += Lc[qw][r][lane];
        float lsum = Oacc[8] + Lc[qw][8][lane];
        u32x2 lb = __builtin_amdgcn_permlane32_swap(__float_as_uint(lsum),
                                                    __float_as_uint(lsum), false, false);
        float inv = frcp(__uint_as_float(lb[0]));
        if (qtok < HW) {
            short* An = (short*)A + ((size_t)n * HW + qtok) * CH + head * 16;
            int2 pk0 = pack4(Oacc[0] * inv, Oacc[1] * inv, Oacc[2] * inv, Oacc[3] * inv);
            int2 pk1 = pack4(Oacc[4] * inv, Oacc[5] * inv, Oacc[6] * inv, Oacc[7] * inv);
            *(int2*)&An[hi * 4] = pk0;
            *(int2*)&An[8 + hi * 4] = pk1;
        }
    }
}

extern "C" void kernel_launch(void* const* d_in, const int* in_sizes, int n_in,
                              void* d_out, int out_size, void* d_ws, size_t ws_size,
                              hipStream_t stream) {
    char* ws = (char*)d_ws;
    bf16*  Wst  = (bf16*)(ws + 256);          // 327680 bf16
    float* Bst  = (float*)(ws + 655616);      // 768 f32
    bf16*  Pad  = (bf16*)(ws + 786432);       // 2048 zeros | 2048 ones
    bf16*  XT   = (bf16*)(ws + 1048576);      // channel-last [n][1296][128]
    bf16*  Zb   = XT + TT;
    bf16*  Qb   = Zb + TT;                    // head-grouped [n][8][1296][16]
    bf16*  Kb   = Qb + TT;
    bf16*  Vb   = Kb + TT;                    // channel-first [n][128][1296]
    bf16*  Ab   = Vb + TT;                    // ~17 MB total

    k_prep<<<1300, 256, 0, stream>>>(d_in[1], d_in[3], d_in[5], d_in[6], d_in[7],
                                     d_in[8], d_in[12], d_in[14], d_in[16],
                                     d_in[2], d_in[4], d_in[9], d_in[13], d_in[15], d_in[17],
                                     Wst, Bst, Pad);
    // n on blockIdx.x (gridDim.x == 8): linear wg id % 8 == n -> per-batch XCD locality
    k_inm<<<dim3(8, 41, 4), 256, 0, stream>>>(d_in[0], d_in[1], Wst, Bst, XT);
    k_cq<<<dim3(8, 41), 512, 0, stream>>>(XT, Wst + 16384, Bst + 128, Wst + 163840,
                                          Pad, Zb, Qb, Kb, Vb);
    k_attn<<<dim3(8, 11, 8), 512, 0, stream>>>(Qb, Kb, Vb, Pad, Ab);
    k_cell<<<dim3(8, 81), 256, 0, stream>>>(Zb, Ab, Wst + 212992, Bst + 256,
                                            Wst + 311296, Bst + 640, d_out, d_in[1]);
}